// Round 12
// baseline (59.363 us; speedup 1.0000x reference)
//
#include <hip/hip_runtime.h>
#include <hip/hip_bf16.h>

// QuantumFeedForward, fully fused:
//   q[n,w] = prod_{v in M_w} cos(theta_v)*cos(x[n,v])   (analytic circuit collapse)
//   out    = relu(q@W1^T+b1) @ W2^T + b2
// 32x32x16 MFMA. H^T = mfma(W1aug-frag, qaug-frag) -> pk-relu -> cvt_pk ->
// v_permlane32_swap -> GEMM A-quads in registers (dataflow verified R9-R11).
// R12: 128-k staging (one vmcnt(0)+s_barrier per TWO kt, 16 total), static
// buffer parity (unrolled pairs -> immediate ds offsets), W1 frags from global
// issued BEFORE the prefetch stage (counted vmcnt, never drains the prefetch),
// v_pk_max_f32 relu. W2 B-frags LDS-staged in fragment order (linear =
// gload_lds-legal and conflict-free ds_read).

typedef __attribute__((ext_vector_type(8))) short bf16x8;
typedef __attribute__((ext_vector_type(16))) float f32x16;
typedef __attribute__((ext_vector_type(8))) unsigned short us8;
typedef unsigned int u32;

#define NTOK  16384
#define EMBED 512
#define FFN   2048
#define NQ    10
#define BM    128
#define BN    128
#define NPAIR 16          // K-pairs of 128 k (2 kt of 64)

__device__ __forceinline__ unsigned short f2bf(float f) {
  union { float f; unsigned int u; } a; a.f = f;
  unsigned int r = a.u + 0x7FFFu + ((a.u >> 16) & 1u);   // RNE
  return (unsigned short)(r >> 16);
}

__device__ __forceinline__ void gload_lds16(const void* g, void* l) {
  __builtin_amdgcn_global_load_lds(
      (const __attribute__((address_space(1))) unsigned int*)g,
      (__attribute__((address_space(3))) unsigned int*)l, 16, 0, 0);
}

// ---------------- K0: fused prep (W2f + Qf + W1f), one launch ----------------
// W2f[((tile*128+kb)*64+l)*8+e] = W2[col=tile*32+(l&31)][k=kb*16+(l>>5)*8+e]
// Qf [(tile*64+l)*8+e]          = qaug[wire=(l>>5)*8+e][token=tile*32+(l&31)]
// W1f[(blk*64+l)*8+e]           = W1aug[wire=(l>>5)*8+e][k=blk*32+(l&31)]
__global__ __launch_bounds__(256) void k_prep(const float* __restrict__ x,
                                              const float* __restrict__ theta,
                                              const float* __restrict__ W1,
                                              const float* __restrict__ b1,
                                              const float* __restrict__ W2,
                                              unsigned short* __restrict__ W2f,
                                              unsigned short* __restrict__ W1f,
                                              unsigned short* __restrict__ Qf) {
  int bb = blockIdx.x;
  if (bb < 512) {                       // ---- W2f: 131072 chunks ----
    int gid = bb * 256 + threadIdx.x;
    int l = gid & 63, kb = (gid >> 6) & 127, tile = gid >> 13;
    int col = tile * 32 + (l & 31);
    int k0 = kb * 16 + (l >> 5) * 8;
    const float* src = W2 + (size_t)col * FFN + k0;
    float4 v0 = *(const float4*)src;
    float4 v1 = *(const float4*)(src + 4);
    us8 o;
    o[0] = f2bf(v0.x); o[1] = f2bf(v0.y); o[2] = f2bf(v0.z); o[3] = f2bf(v0.w);
    o[4] = f2bf(v1.x); o[5] = f2bf(v1.y); o[6] = f2bf(v1.z); o[7] = f2bf(v1.w);
    *(us8*)(W2f + (size_t)gid * 8) = o;
  } else if (bb < 640) {                // ---- Qf: 32768 chunks ----
    int gid = (bb - 512) * 256 + threadIdx.x;
    int l = gid & 63, tile = gid >> 6;
    int tok = tile * 32 + (l & 31), g = l >> 5;
    const int masks[NQ] = {0x2AB,0x3FD,0x3FA,0x3F5,0x3EA,0x3D5,0x3AA,0x355,0x2AA,0x155};
    float z[NQ], qv[NQ];
#pragma unroll
    for (int w = 0; w < NQ; ++w)
      z[w] = __builtin_cosf(x[(size_t)tok * EMBED + w]) * __builtin_cosf(theta[w]);
#pragma unroll
    for (int w = 0; w < NQ; ++w) {
      float p = 1.f;
#pragma unroll
      for (int v = 0; v < NQ; ++v)
        if ((masks[w] >> v) & 1) p *= z[v];
      qv[w] = p;
    }
    us8 o = (us8)0;
    if (g == 0) {
#pragma unroll
      for (int e = 0; e < 8; ++e) o[e] = f2bf(qv[e]);
    } else {
      o[0] = f2bf(qv[8]); o[1] = f2bf(qv[9]); o[2] = f2bf(1.f);
    }
    *(us8*)(Qf + (size_t)gid * 8) = o;
  } else {                              // ---- W1f: 4096 chunks ----
    int gid = (bb - 640) * 256 + threadIdx.x;
    int l = gid & 63, blk = gid >> 6;
    int k = blk * 32 + (l & 31);
    int wg = (l >> 5) * 8;
    us8 o;
#pragma unroll
    for (int e = 0; e < 8; ++e) {
      int wire = wg + e;
      float v = (wire < NQ) ? W1[k * NQ + wire] : (wire == NQ ? b1[k] : 0.f);
      o[e] = f2bf(v);
    }
    *(us8*)(W1f + (size_t)gid * 8) = o;
  }
}

// ---------------- K1: fused H-gen + GEMM, 4 waves/SIMD ----------------
__global__ __launch_bounds__(512, 4) void k_fused(const unsigned short* __restrict__ Qf,
                                                  const unsigned short* __restrict__ W1f,
                                                  const unsigned short* __restrict__ W2f,
                                                  const float* __restrict__ b2,
                                                  float* __restrict__ out) {
  __shared__ short Bw[2][32 * 64 * 8];   // 2 x 32KB: [tile2*8+kbl][lane][8], frag order

  // XCD-aware bijective swizzle: 512 blocks, 64 consecutive per XCD; n fastest.
  int bid = blockIdx.x;
  int swz = (bid & 7) * 64 + (bid >> 3);
  const int m0 = (swz >> 2) * BM;
  const int n0 = (swz & 3) * BN;
  const int tid  = threadIdx.x;
  const int lane = tid & 63;
  const int wave = tid >> 6;           // 8 waves: 4 (M) x 2 (N), 32x64 tiles
  const int wm = wave >> 1, wn = wave & 1;
  const int h = lane >> 5, t31 = lane & 31;
  const int nt0 = n0 >> 5;             // global col-tile base (4 tiles of 32)

  // q_aug B-frag for this wave's 32 tokens (single load, register-resident)
  bf16x8 qf = *(const bf16x8*)&Qf[(((size_t)(m0 >> 5) + wm) * 64 + lane) * 8];

  f32x16 acc[2] = {};

  // Stage one 128-k pair: 2048 Bw chunks (4/thread).
#define STAGE(P, B)                                                             \
  { _Pragma("unroll")                                                           \
    for (int hf = 0; hf < 4; ++hf) {                                            \
      int ch = hf * 512 + tid;                                                  \
      int tile2 = ch >> 9, kbl = (ch >> 6) & 7, ln = ch & 63;                   \
      gload_lds16(&W2f[(((size_t)(nt0 + tile2) * 128 + (P) * 8 + kbl) * 64 + ln) * 8], \
                  &Bw[B][ch * 8]);                                              \
    } }

  // H^T = mfma(W1aug, qaug); v_pk_max relu; cvt_pk; permlane32_swap -> A-quads
#define HGEN1(WF, AQ0, AQ1)                                                     \
  { f32x16 zz = {};                                                             \
    f32x16 d = __builtin_amdgcn_mfma_f32_32x32x16_bf16((WF), qf, zz, 0, 0, 0);  \
    d = __builtin_elementwise_max(d, zz);                                       \
    u32 dw0, dw1, dw2, dw3, dw4, dw5, dw6, dw7;                                 \
    asm("v_cvt_pk_bf16_f32 %0, %1, %2":"=v"(dw0):"v"(d[0]),"v"(d[1]));          \
    asm("v_cvt_pk_bf16_f32 %0, %1, %2":"=v"(dw1):"v"(d[2]),"v"(d[3]));          \
    asm("v_cvt_pk_bf16_f32 %0, %1, %2":"=v"(dw2):"v"(d[4]),"v"(d[5]));          \
    asm("v_cvt_pk_bf16_f32 %0, %1, %2":"=v"(dw3):"v"(d[6]),"v"(d[7]));          \
    asm("v_cvt_pk_bf16_f32 %0, %1, %2":"=v"(dw4):"v"(d[8]),"v"(d[9]));          \
    asm("v_cvt_pk_bf16_f32 %0, %1, %2":"=v"(dw5):"v"(d[10]),"v"(d[11]));        \
    asm("v_cvt_pk_bf16_f32 %0, %1, %2":"=v"(dw6):"v"(d[12]),"v"(d[13]));        \
    asm("v_cvt_pk_bf16_f32 %0, %1, %2":"=v"(dw7):"v"(d[14]),"v"(d[15]));        \
    asm("v_permlane32_swap_b32 %0, %1" : "+v"(dw0), "+v"(dw2));                 \
    asm("v_permlane32_swap_b32 %0, %1" : "+v"(dw1), "+v"(dw3));                 \
    asm("v_permlane32_swap_b32 %0, %1" : "+v"(dw4), "+v"(dw6));                 \
    asm("v_permlane32_swap_b32 %0, %1" : "+v"(dw5), "+v"(dw7));                 \
    union { u32 u[4]; bf16x8 v; } u0, u1;                                       \
    u0.u[0]=dw0; u0.u[1]=dw1; u0.u[2]=dw2; u0.u[3]=dw3;                         \
    u1.u[0]=dw4; u1.u[1]=dw5; u1.u[2]=dw6; u1.u[3]=dw7;                         \
    AQ0 = u0.v; AQ1 = u1.v; }

  // One 64-k tile (Q = 0/1 within the pair), buffer B static.
#define KTBODY(Q, B, WFA, WFB)                                                  \
  { bf16x8 aq00, aq01, aq10, aq11;                                              \
    HGEN1(WFA, aq00, aq01);                                                     \
    HGEN1(WFB, aq10, aq11);                                                     \
    _Pragma("unroll")                                                           \
    for (int j = 0; j < 2; ++j) {                                               \
      bf16x8 bg0 = *(const bf16x8*)&Bw[B][(((wn * 2 + j) * 8 + (Q) * 4 + 0) * 64 + lane) * 8]; \
      bf16x8 bg1 = *(const bf16x8*)&Bw[B][(((wn * 2 + j) * 8 + (Q) * 4 + 1) * 64 + lane) * 8]; \
      bf16x8 bg2 = *(const bf16x8*)&Bw[B][(((wn * 2 + j) * 8 + (Q) * 4 + 2) * 64 + lane) * 8]; \
      bf16x8 bg3 = *(const bf16x8*)&Bw[B][(((wn * 2 + j) * 8 + (Q) * 4 + 3) * 64 + lane) * 8]; \
      __builtin_amdgcn_s_setprio(1);                                            \
      acc[j] = __builtin_amdgcn_mfma_f32_32x32x16_bf16(aq00, bg0, acc[j], 0, 0, 0); \
      acc[j] = __builtin_amdgcn_mfma_f32_32x32x16_bf16(aq01, bg1, acc[j], 0, 0, 0); \
      acc[j] = __builtin_amdgcn_mfma_f32_32x32x16_bf16(aq10, bg2, acc[j], 0, 0, 0); \
      acc[j] = __builtin_amdgcn_mfma_f32_32x32x16_bf16(aq11, bg3, acc[j], 0, 0, 0); \
      __builtin_amdgcn_s_setprio(0);                                            \
    } }

  // One 128-k pair. wf loads issued BEFORE the prefetch STAGE so the compiler's
  // wait for them is a counted vmcnt (the 8 stage loads stay in flight).
#define PAIR(P, B)                                                              \
  {                                                                             \
    asm volatile("s_waitcnt vmcnt(0)" ::: "memory");   /* stage(P) landed */    \
    __builtin_amdgcn_s_barrier();                      /* buf B^1 reads done */ \
    asm volatile("" ::: "memory");                                              \
    bf16x8 wf0 = *(const bf16x8*)&W1f[(((size_t)(P) * 4 + 0) * 64 + lane) * 8]; \
    bf16x8 wf1 = *(const bf16x8*)&W1f[(((size_t)(P) * 4 + 1) * 64 + lane) * 8]; \
    bf16x8 wf2 = *(const bf16x8*)&W1f[(((size_t)(P) * 4 + 2) * 64 + lane) * 8]; \
    bf16x8 wf3 = *(const bf16x8*)&W1f[(((size_t)(P) * 4 + 3) * 64 + lane) * 8]; \
    if ((P) + 1 < NPAIR) STAGE((P) + 1, (B) ^ 1);                               \
    KTBODY(0, B, wf0, wf1);                                                     \
    KTBODY(1, B, wf2, wf3);                                                     \
  }

  // ---- prologue: stage pair 0 ----
  STAGE(0, 0);

  // ---- main loop: two pairs per iteration (static buffer parity) ----
  for (int p2 = 0; p2 < NPAIR / 2; ++p2) {
    PAIR(2 * p2,     0);
    PAIR(2 * p2 + 1, 1);
  }

  // ---- epilogue: out = acc + b2 ----
#pragma unroll
  for (int j = 0; j < 2; ++j) {
    const int col = n0 + wn * 64 + j * 32 + t31;
    const float bbv = b2[col];
#pragma unroll
    for (int r = 0; r < 16; ++r) {
      int tok = m0 + wm * 32 + (r & 3) + 8 * (r >> 2) + 4 * h;
      out[(size_t)tok * EMBED + col] = acc[j][r] + bbv;
    }
  }
#undef STAGE
#undef HGEN1
#undef KTBODY
#undef PAIR
}

extern "C" void kernel_launch(void* const* d_in, const int* in_sizes, int n_in,
                              void* d_out, int out_size, void* d_ws, size_t ws_size,
                              hipStream_t stream) {
  const float* x     = (const float*)d_in[0];
  const float* theta = (const float*)d_in[1];
  const float* W1    = (const float*)d_in[2];
  const float* b1    = (const float*)d_in[3];
  const float* W2    = (const float*)d_in[4];
  const float* b2    = (const float*)d_in[5];
  float* out = (float*)d_out;

  char* ws = (char*)d_ws;
  unsigned short* W2f = (unsigned short*)ws;                          // 2 MB
  unsigned short* W1f = (unsigned short*)(ws + (2u << 20));           // 64 KB
  unsigned short* Qfg = (unsigned short*)(ws + (2u << 20) + (64u << 10)); // 512 KB

  k_prep <<<656, 256, 0, stream>>>(x, theta, W1, b1, W2, W2f, W1f, Qfg);
  k_fused<<<(NTOK / BM) * (EMBED / BN), 512, 0, stream>>>(Qfg, W1f, W2f, b2, out);
}